// Round 1
// baseline (583.369 us; speedup 1.0000x reference)
//
#include <hip/hip_runtime.h>

#define HH 128
#define WW 128
#define NPIX (4*128*128)          // 65536
#define OUT_ELEMS (NPIX*64)       // 4194304
#define ATTN_ELEMS (NPIX*625)     // 40960000

__device__ __forceinline__ int div25(int v) { return (v * 5243) >> 17; }   // exact for 0..2600
__device__ __forceinline__ int div5(int v)  { return (v * 205) >> 10; }    // exact for 0..1000

// ---------------------------------------------------------------------------
// K1: 1x1 convs q/k/v (+ copy x into out as fold-init). One wave per pixel.
// ---------------------------------------------------------------------------
__global__ __launch_bounds__(256) void k1_qkv(
    const float* __restrict__ x,
    const float* __restrict__ Wq, const float* __restrict__ bq,
    const float* __restrict__ Wk, const float* __restrict__ bk,
    const float* __restrict__ Wv, const float* __restrict__ bv,
    float* __restrict__ qws, float* __restrict__ kws, float* __restrict__ vws,
    float* __restrict__ out)
{
    __shared__ float sWv[64 * 65];    // padded rows: bank (o+c)%32
    __shared__ float sWqk[16 * 65];   // q rows 0..7, k rows 8..15
    __shared__ float sx[4][64];

    int t = threadIdx.x;
    for (int e = t; e < 64 * 64; e += 256) {
        int o = e >> 6, c = e & 63;
        sWv[o * 65 + c] = Wv[e];
    }
    for (int e = t; e < 8 * 64; e += 256) {
        int o = e >> 6, c = e & 63;
        sWqk[o * 65 + c]       = Wq[e];
        sWqk[(o + 8) * 65 + c] = Wk[e];
    }

    int wid = t >> 6, lane = t & 63;
    int pix = blockIdx.x * 4 + wid;
    const float* xp = x + (size_t)pix * 64;
    float xv = xp[lane];
    sx[wid][lane] = xv;
    __syncthreads();

    const float* xb = sx[wid];
    bool isq = lane < 8;
    bool isk = (lane >= 8) && (lane < 16);
    float accv = bv[lane];
    float accq = isq ? bq[lane] : (isk ? bk[lane - 8] : 0.f);
    const float* wr  = sWv + lane * 65;
    const float* wr2 = sWqk + (lane & 7) * 65 + (isk ? 8 * 65 : 0);

    #pragma unroll
    for (int c = 0; c < 64; ++c) {
        float xc = xb[c];
        accv = fmaf(xc, wr[c], accv);
        accq = fmaf(xc, wr2[c], accq);
    }

    vws[(size_t)pix * 64 + lane] = accv;
    out[(size_t)pix * 64 + lane] = xv;          // fold-init: out = x (+ gamma*fold via atomics)
    if (isq)      qws[(size_t)pix * 8 + lane] = accq;
    else if (isk) kws[(size_t)pix * 8 + (lane - 8)] = accq;
}

// ---------------------------------------------------------------------------
// K2: per-pixel local attention. One wave per pixel (4 waves / 256-thr block).
// ---------------------------------------------------------------------------
__global__ __launch_bounds__(256) void k2_attn(
    const float* __restrict__ qws, const float* __restrict__ kws,
    const float* __restrict__ vws, const float* __restrict__ gamma,
    float* __restrict__ out, float* __restrict__ attn)
{
    __shared__ float sV[4][1632];   // Vraw [25][65] (padded); later reused as localbuf[1600]
    __shared__ float sQ[4][200];    // Qflat[f], f = cq*25 + p
    __shared__ float sK[4][200];
    __shared__ float sE[4][704];    // logits/exp rows [25][28] (pad 28 -> 16B-aligned rows)
    __shared__ float sR[4][32];     // 1/rowsum

    int t = threadIdx.x, wid = t >> 6, lane = t & 63;
    int pix = blockIdx.x * 4 + wid;
    int b = pix >> 14;
    int y = (pix >> 7) & 127;
    int x = pix & 127;

    float* V  = sV[wid];
    float* Qs = sQ[wid];
    float* Ks = sK[wid];
    float* E  = sE[wid];
    float* R  = sR[wid];

    // ---- stage V patch coalesced: Vraw[p][cv] = v(cv, y+di-2, x+dj-2), zero-padded
    const float* vb = vws + (size_t)(b << 14) * 64;
    #pragma unroll
    for (int p = 0; p < 25; ++p) {
        int i5 = div5(p);
        int yy = y + i5 - 2, xx = x + (p - i5 * 5) - 2;
        float val = 0.f;
        if ((unsigned)yy < 128u && (unsigned)xx < 128u)
            val = vb[((yy << 7) + xx) * 64 + lane];
        V[p * 65 + lane] = val;
    }
    // ---- stage Q,K flat: Qf[f] = q(cq=f/25, patch p=f%25)
    const float* qb = qws + (size_t)(b << 14) * 8;
    const float* kb = kws + (size_t)(b << 14) * 8;
    #pragma unroll
    for (int i = 0; i < 4; ++i) {
        int e = lane + i * 64;
        if (e < 200) {
            int cq = div25(e);
            int p  = e - cq * 25;
            int i5 = div5(p);
            int yy = y + i5 - 2, xx = x + (p - i5 * 5) - 2;
            float qv = 0.f, kv = 0.f;
            if ((unsigned)yy < 128u && (unsigned)xx < 128u) {
                int off = ((yy << 7) + xx) * 8 + cq;
                qv = qb[off];
                kv = kb[off];
            }
            Qs[e] = qv;
            Ks[e] = kv;
        }
    }
    __syncthreads();

    // ---- V fragment to registers: vr[m] = Vflat[m*64+lane]
    float vr[25];
    #pragma unroll
    for (int m = 0; m < 25; ++m) {
        int g  = m * 64 + lane;
        int cv = div25(g);
        int p  = g - cv * 25;
        vr[m] = V[p * 65 + cv];
    }

    // ---- logits[n][m] = sum_{c<8} Qf[n*8+c]*Kf[m*8+c]
    #pragma unroll
    for (int i = 0; i < 10; ++i) {
        int e = lane + (i << 6);
        if (e < 625) {
            int n = div25(e), m = e - n * 25;
            const float4* qr = (const float4*)(Qs + (n << 3));
            const float4* kr = (const float4*)(Ks + (m << 3));
            float4 q0 = qr[0], q1 = qr[1], k0 = kr[0], k1 = kr[1];
            float s = q0.x * k0.x + q0.y * k0.y + q0.z * k0.z + q0.w * k0.w
                    + q1.x * k1.x + q1.y * k1.y + q1.z * k1.z + q1.w * k1.w;
            E[n * 28 + m] = s;
        }
    }
    __syncthreads();

    // ---- softmax rows (lanes 0..24, row n = lane); keep unnormalized exp + 1/sum
    if (lane < 25) {
        float* row = E + lane * 28;
        float mx = -3.4e38f;
        #pragma unroll
        for (int m = 0; m < 25; ++m) mx = fmaxf(mx, row[m]);
        float s = 0.f;
        #pragma unroll
        for (int m = 0; m < 25; ++m) {
            float ev = __expf(row[m] - mx);
            row[m] = ev;
            s += ev;
        }
        R[lane] = 1.f / s;
    }
    __syncthreads();

    // ---- write normalized attn [n][m], coalesced
    float* ab = attn + (size_t)pix * 625;
    #pragma unroll
    for (int i = 0; i < 10; ++i) {
        int e = lane + (i << 6);
        if (e < 625) {
            int n = div25(e), m = e - n * 25;
            ab[e] = E[n * 28 + m] * R[n];
        }
    }

    // ---- PV: acc[n] = (sum_m exp[n][m]*vr[m]) * (1/sum) * gamma
    float g0 = gamma[0];
    float acc[25];
    #pragma unroll
    for (int n = 0; n < 25; ++n) {
        const float4* er = (const float4*)(E + n * 28);
        float a = E[n * 28 + 24] * vr[24];
        #pragma unroll
        for (int q4 = 0; q4 < 6; ++q4) {
            float4 ev = er[q4];
            a = fmaf(ev.x, vr[q4 * 4 + 0], a);
            a = fmaf(ev.y, vr[q4 * 4 + 1], a);
            a = fmaf(ev.z, vr[q4 * 4 + 2], a);
            a = fmaf(ev.w, vr[q4 * 4 + 3], a);
        }
        acc[n] = a * (R[n] * g0);
    }
    __syncthreads();

    // ---- remap local [n*64+lane] -> [c*25+p] via LDS (reuse V), then fold-scatter
    float* LB = V;
    #pragma unroll
    for (int n = 0; n < 25; ++n) LB[(n << 6) + lane] = acc[n];
    __syncthreads();

    float* ob = out + (size_t)(b << 14) * 64;
    #pragma unroll
    for (int p = 0; p < 25; ++p) {
        int i5 = div5(p);
        int ty = y + i5 - 2, tx = x + (p - i5 * 5) - 2;
        if ((unsigned)ty < 128u && (unsigned)tx < 128u) {
            float val = LB[lane * 25 + p];
            atomicAdd(ob + ((ty << 7) + tx) * 64 + lane, val);
        }
    }
}

// ---------------------------------------------------------------------------
extern "C" void kernel_launch(void* const* d_in, const int* in_sizes, int n_in,
                              void* d_out, int out_size, void* d_ws, size_t ws_size,
                              hipStream_t stream)
{
    const float* x  = (const float*)d_in[0];
    const float* Wq = (const float*)d_in[1];
    const float* bq = (const float*)d_in[2];
    const float* Wk = (const float*)d_in[3];
    const float* bk = (const float*)d_in[4];
    const float* Wv = (const float*)d_in[5];
    const float* bv = (const float*)d_in[6];
    const float* gm = (const float*)d_in[7];

    float* out  = (float*)d_out;               // [4,128,128,64]
    float* attn = out + OUT_ELEMS;             // [4,128,128,25,25]

    float* qws = (float*)d_ws;                 // [NPIX][8]
    float* kws = qws + (size_t)NPIX * 8;       // [NPIX][8]
    float* vws = kws + (size_t)NPIX * 8;       // [NPIX][64]

    hipLaunchKernelGGL(k1_qkv, dim3(NPIX / 4), dim3(256), 0, stream,
                       x, Wq, bq, Wk, bk, Wv, bv, qws, kws, vws, out);
    hipLaunchKernelGGL(k2_attn, dim3(NPIX / 4), dim3(256), 0, stream,
                       qws, kws, vws, gm, out, attn);
}